// Round 1
// baseline (2827.711 us; speedup 1.0000x reference)
//
#include <hip/hip_runtime.h>

// Swin window attention, fully fused, fp32. One block per window.
// B=4096 windows, N=64 tokens, C=180, H=6 heads, D=30, WNum=1024 masks.
//
// LDS union (floats), total 39040 f32 = 156,160 B (< 163,840 gfx950 max):
//   [0     .. 12511]  xsT  [184][68]  (phase 1-2: x transposed, k-major)
//                     zsT  [184][68]  (phase 6: z transposed, e-major)
//   [12512 .. 21215]  wst  [2][8][544] (phase 2: w_qkv row chunks, dbuf)
//   [0     .. 23039]  qkT  [360][64]  (phase 3-5: q,k transposed, d-major)
//   [23040 .. 34815]  vbuf [64][184]  (phase 3-5: v row-major)
//                     wps  [2][8][184] (phase 6: w_proj row chunks, dbuf)
//   [34816 .. 39039]  sT   [64][66]   (phase 4-5: scores transposed [j][i])

#define BLK 576

__global__ __launch_bounds__(BLK, 1)
void swin_attn_f32(const float* __restrict__ xg_all,
                   const float* __restrict__ mask_all,
                   const float* __restrict__ wqkv,
                   const float* __restrict__ btab,
                   const float* __restrict__ wproj,
                   const float* __restrict__ bproj,
                   float* __restrict__ outg)
{
    __shared__ float smem[39040];
    float* const xsT  = smem;            // [184][68]
    float* const wst  = smem + 12512;    // [2][8][544]
    float* const qkT  = smem;            // [360][64]
    float* const zsT  = smem;            // [184][68]
    float* const vbuf = smem + 23040;    // [64][184]
    float* const wps  = smem + 23040;    // [2][8][184]
    float* const sT   = smem + 34816;    // [64][66]

    const int b   = blockIdx.x;
    const int tid = threadIdx.x;
    const float* xg    = xg_all  + (size_t)b * (64 * 180);
    const float* maskw = mask_all + (size_t)(b & 1023) * 4096;

    // ---------------- phase 1: load x -> xsT (transposed), pad rows 180..183
    for (int e = tid; e < 2880; e += BLK) {              // 2880 = 64*180/4, exactly 5 iters
        const int elem = e * 4;
        const int i = elem / 180;
        const int k = elem - i * 180;                    // 180 % 4 == 0: no row crossing
        const float4 v = *reinterpret_cast<const float4*>(xg + elem);
        xsT[(k + 0) * 68 + i] = v.x;
        xsT[(k + 1) * 68 + i] = v.y;
        xsT[(k + 2) * 68 + i] = v.z;
        xsT[(k + 3) * 68 + i] = v.w;
    }
    for (int e = tid; e < 4 * 68; e += BLK) {
        const int kk = e / 68;
        xsT[(180 + kk) * 68 + (e - kk * 68)] = 0.f;
    }
    // stage w_qkv chunk 0 into wst buf0 (region disjoint from xsT)
    for (int e = tid; e < 4352; e += BLK) {
        const int kr = e / 544;
        const int m  = e - kr * 544;
        wst[e] = (m < 540) ? wqkv[kr * 540 + m] : 0.f;
    }
    __syncthreads();

    // ---------------- phase 2: qkv GEMM  (M=64 rows i, N=544 cols m, K=184)
    float acc[8][8];
    #pragma unroll
    for (int rr = 0; rr < 8; rr++)
        #pragma unroll
        for (int cc = 0; cc < 8; cc++) acc[rr][cc] = 0.f;

    const int r2 = tid / 68;
    const int c2 = tid - r2 * 68;
    const int i0 = r2 * 8, m0 = c2 * 8;                  // valid for tid < 544

    for (int t = 0; t < 23; t++) {
        const int bo = (t & 1) * 4352;
        if (t < 22) {                                    // stage next chunk into other buf
            const int k0n = t * 8 + 8;
            const int bon = 4352 - bo;
            for (int e = tid; e < 4352; e += BLK) {
                const int kr = e / 544;
                const int m  = e - kr * 544;
                const int k  = k0n + kr;
                wst[bon + e] = (k < 180 && m < 540) ? wqkv[k * 540 + m] : 0.f;
            }
        }
        if (tid < 544) {
            const int k0 = t * 8;
            #pragma unroll
            for (int kr = 0; kr < 8; kr++) {
                const float4 a0 = *reinterpret_cast<const float4*>(xsT + (k0 + kr) * 68 + i0);
                const float4 a1 = *reinterpret_cast<const float4*>(xsT + (k0 + kr) * 68 + i0 + 4);
                const float4 b0 = *reinterpret_cast<const float4*>(wst + bo + kr * 544 + m0);
                const float4 b1 = *reinterpret_cast<const float4*>(wst + bo + kr * 544 + m0 + 4);
                const float av[8] = {a0.x, a0.y, a0.z, a0.w, a1.x, a1.y, a1.z, a1.w};
                const float bv[8] = {b0.x, b0.y, b0.z, b0.w, b1.x, b1.y, b1.z, b1.w};
                #pragma unroll
                for (int rr = 0; rr < 8; rr++)
                    #pragma unroll
                    for (int cc = 0; cc < 8; cc++)
                        acc[rr][cc] += av[rr] * bv[cc];
            }
        }
        __syncthreads();
    }

    // ---------------- phase 3: write back qkv (q,k transposed; v row-major)
    if (tid < 544) {
        if (m0 < 360) {                                  // q,k -> qkT[m][i]
            #pragma unroll
            for (int cc = 0; cc < 8; cc++) {
                const float4 w0 = make_float4(acc[0][cc], acc[1][cc], acc[2][cc], acc[3][cc]);
                const float4 w1 = make_float4(acc[4][cc], acc[5][cc], acc[6][cc], acc[7][cc]);
                *reinterpret_cast<float4*>(qkT + (m0 + cc) * 64 + i0)     = w0;
                *reinterpret_cast<float4*>(qkT + (m0 + cc) * 64 + i0 + 4) = w1;
            }
        } else {                                         // v -> vbuf[i][e]
            #pragma unroll
            for (int rr = 0; rr < 8; rr++) {
                const float4 w0 = make_float4(acc[rr][0], acc[rr][1], acc[rr][2], acc[rr][3]);
                const float4 w1 = make_float4(acc[rr][4], acc[rr][5], acc[rr][6], acc[rr][7]);
                *reinterpret_cast<float4*>(vbuf + (i0 + rr) * 184 + (m0 - 360))     = w0;
                *reinterpret_cast<float4*>(vbuf + (i0 + rr) * 184 + (m0 - 360) + 4) = w1;
            }
        }
    }
    __syncthreads();

    // ---------------- phases 4-5: per-head attention (fully unrolled for static zacc)
    const int di  = tid / 15;
    const int dc  = tid - di * 15;
    const int zi0 = di * 2, zd0 = dc * 2;                // valid for tid < 480
    float zacc[6][2][2];
    #pragma unroll
    for (int h = 0; h < 6; h++) {
        zacc[h][0][0] = 0.f; zacc[h][0][1] = 0.f;
        zacc[h][1][0] = 0.f; zacc[h][1][1] = 0.f;
    }
    const float scale = 0.18257418583505537f;            // 1/sqrt(30)

    #pragma unroll
    for (int h = 0; h < 6; h++) {
        // --- QK^T: 256 threads, 4x4 tiles, outer-product over d
        if (tid < 256) {
            const int ir = tid >> 4, jr = tid & 15;
            const int si0 = ir * 4, sj0 = jr * 4;
            float sc[4][4];
            #pragma unroll
            for (int ii = 0; ii < 4; ii++)
                #pragma unroll
                for (int jj = 0; jj < 4; jj++) sc[ii][jj] = 0.f;
            const float* qrow = qkT + (h * 30) * 64;
            const float* krow = qkT + (180 + h * 30) * 64;
            for (int d = 0; d < 30; d++) {
                const float4 qa = *reinterpret_cast<const float4*>(qrow + d * 64 + si0);
                const float4 kb = *reinterpret_cast<const float4*>(krow + d * 64 + sj0);
                const float qv[4] = {qa.x, qa.y, qa.z, qa.w};
                const float kv[4] = {kb.x, kb.y, kb.z, kb.w};
                #pragma unroll
                for (int ii = 0; ii < 4; ii++)
                    #pragma unroll
                    for (int jj = 0; jj < 4; jj++)
                        sc[ii][jj] += qv[ii] * kv[jj];
            }
            // epilogue: scale + rel-pos bias + mask, store transposed sT[j][i]
            #pragma unroll
            for (int ii = 0; ii < 4; ii++) {
                const int i  = si0 + ii;
                const int yi = i >> 3, xi = i & 7;
                const float4 mk = *reinterpret_cast<const float4*>(maskw + i * 64 + sj0);
                const float mkv[4] = {mk.x, mk.y, mk.z, mk.w};
                #pragma unroll
                for (int jj = 0; jj < 4; jj++) {
                    const int j   = sj0 + jj;
                    const int rel = (yi - (j >> 3) + 7) * 15 + (xi - (j & 7) + 7);
                    sT[j * 66 + i] = sc[ii][jj] * scale + btab[rel * 6 + h] + mkv[jj];
                }
            }
        }
        __syncthreads();
        // --- softmax over j: 512 threads, 8 lanes per row
        if (tid < 512) {
            const int i = tid >> 3, u = tid & 7;
            float vals[8];
            float mx = -1e30f;
            #pragma unroll
            for (int q = 0; q < 8; q++) {
                vals[q] = sT[(u * 8 + q) * 66 + i];
                mx = fmaxf(mx, vals[q]);
            }
            mx = fmaxf(mx, __shfl_xor(mx, 1));
            mx = fmaxf(mx, __shfl_xor(mx, 2));
            mx = fmaxf(mx, __shfl_xor(mx, 4));
            float s = 0.f;
            #pragma unroll
            for (int q = 0; q < 8; q++) { vals[q] = __expf(vals[q] - mx); s += vals[q]; }
            s += __shfl_xor(s, 1);
            s += __shfl_xor(s, 2);
            s += __shfl_xor(s, 4);
            const float inv = 1.0f / s;
            #pragma unroll
            for (int q = 0; q < 8; q++) sT[(u * 8 + q) * 66 + i] = vals[q] * inv;
        }
        __syncthreads();
        // --- PV: 480 threads, 2x2 tiles, outer-product over j; z stays in regs
        if (tid < 480) {
            const float* vcol = vbuf + h * 30 + zd0;
            #pragma unroll 4
            for (int j = 0; j < 64; j++) {
                const float2 a  = *reinterpret_cast<const float2*>(sT + j * 66 + zi0);
                const float2 vv = *reinterpret_cast<const float2*>(vcol + j * 184);
                zacc[h][0][0] += a.x * vv.x;
                zacc[h][0][1] += a.x * vv.y;
                zacc[h][1][0] += a.y * vv.x;
                zacc[h][1][1] += a.y * vv.y;
            }
        }
        __syncthreads();
    }

    // ---------------- phase 6: z -> zsT (transposed), proj GEMM, store
    if (tid < 480) {
        #pragma unroll
        for (int h = 0; h < 6; h++)
            #pragma unroll
            for (int cc = 0; cc < 2; cc++)
                #pragma unroll
                for (int rr = 0; rr < 2; rr++)
                    zsT[(h * 30 + zd0 + cc) * 68 + zi0 + rr] = zacc[h][rr][cc];
    }
    for (int e = tid; e < 4 * 68; e += BLK) {            // zero pad rows 180..183
        const int kk = e / 68;
        zsT[(180 + kk) * 68 + (e - kk * 68)] = 0.f;
    }
    // stage w_proj chunk 0 (vbuf region is dead)
    for (int e = tid; e < 1472; e += BLK) {
        const int kr = e / 184;
        const int nn = e - kr * 184;
        wps[e] = (nn < 180) ? wproj[kr * 180 + nn] : 0.f;
    }
    __syncthreads();

    float pacc[8][8];
    #pragma unroll
    for (int rr = 0; rr < 8; rr++)
        #pragma unroll
        for (int cc = 0; cc < 8; cc++) pacc[rr][cc] = 0.f;
    const int pr = tid / 23;
    const int pc = tid - pr * 23;
    const int pi0 = pr * 8, n0 = pc * 8;                 // valid for tid < 184

    for (int t = 0; t < 23; t++) {
        const int bo = (t & 1) * 1472;
        if (t < 22) {
            const int k0n = t * 8 + 8;
            const int bon = 1472 - bo;
            for (int e = tid; e < 1472; e += BLK) {
                const int kr = e / 184;
                const int nn = e - kr * 184;
                const int k  = k0n + kr;
                wps[bon + e] = (k < 180 && nn < 180) ? wproj[k * 180 + nn] : 0.f;
            }
        }
        if (tid < 184) {
            const int k0 = t * 8;
            #pragma unroll
            for (int kr = 0; kr < 8; kr++) {
                const float4 a0 = *reinterpret_cast<const float4*>(zsT + (k0 + kr) * 68 + pi0);
                const float4 a1 = *reinterpret_cast<const float4*>(zsT + (k0 + kr) * 68 + pi0 + 4);
                const float4 b0 = *reinterpret_cast<const float4*>(wps + bo + kr * 184 + n0);
                const float4 b1 = *reinterpret_cast<const float4*>(wps + bo + kr * 184 + n0 + 4);
                const float av[8] = {a0.x, a0.y, a0.z, a0.w, a1.x, a1.y, a1.z, a1.w};
                const float bv[8] = {b0.x, b0.y, b0.z, b0.w, b1.x, b1.y, b1.z, b1.w};
                #pragma unroll
                for (int rr = 0; rr < 8; rr++)
                    #pragma unroll
                    for (int cc = 0; cc < 8; cc++)
                        pacc[rr][cc] += av[rr] * bv[cc];
            }
        }
        __syncthreads();
    }

    if (tid < 184) {
        float bp[8];
        #pragma unroll
        for (int cc = 0; cc < 8; cc++) {
            const int n = n0 + cc;
            bp[cc] = (n < 180) ? bproj[n] : 0.f;
        }
        float* og = outg + (size_t)b * 11520;
        #pragma unroll
        for (int rr = 0; rr < 8; rr++) {
            const float4 o0 = make_float4(pacc[rr][0] + bp[0], pacc[rr][1] + bp[1],
                                          pacc[rr][2] + bp[2], pacc[rr][3] + bp[3]);
            *reinterpret_cast<float4*>(og + (pi0 + rr) * 180 + n0) = o0;
            if (n0 + 7 < 180) {
                const float4 o1 = make_float4(pacc[rr][4] + bp[4], pacc[rr][5] + bp[5],
                                              pacc[rr][6] + bp[6], pacc[rr][7] + bp[7]);
                *reinterpret_cast<float4*>(og + (pi0 + rr) * 180 + n0 + 4) = o1;
            }
        }
    }
}

extern "C" void kernel_launch(void* const* d_in, const int* in_sizes, int n_in,
                              void* d_out, int out_size, void* d_ws, size_t ws_size,
                              hipStream_t stream) {
    const float* windows = (const float*)d_in[0];
    const float* mask    = (const float*)d_in[1];
    const float* wqkv    = (const float*)d_in[2];
    const float* btab    = (const float*)d_in[3];
    const float* wproj   = (const float*)d_in[4];
    const float* bproj   = (const float*)d_in[5];
    hipLaunchKernelGGL(swin_attn_f32, dim3(4096), dim3(BLK), 0, stream,
                       windows, mask, wqkv, btab, wproj, bproj, (float*)d_out);
}

// Round 2
// 413.437 us; speedup vs baseline: 6.8395x; 6.8395x over previous
//
#include <hip/hip_runtime.h>

// Swin window attention via bf16 MFMA. One block (384 thr = 6 waves) per window.
// B=4096, N=64, C=180, H=6, D=30 (pad 32), WNum=1024.
//
// d_ws layout (written by prep_kernel every launch):
//   [0)       wqkvT  bf16 [544][192]  (n-major, k contiguous, zero-padded)
//   [208896)  wprojT bf16 [192][192]
//   [282624)  relb   f32  [6][64][64]  rel-pos bias pre-gathered
//
// LDS (shorts, 159744 B total):
//   xb/zb [64][200]   qb [64][200]   kb [64][200]   vT [192][72]   pb 6x[64][72]

typedef __bf16 bf16;
typedef bf16 bf16x8 __attribute__((ext_vector_type(8)));
typedef bf16 bf16x4 __attribute__((ext_vector_type(4)));
typedef float f32x4 __attribute__((ext_vector_type(4)));

#define MFMA(a, b, c) __builtin_amdgcn_mfma_f32_16x16x32_bf16(a, b, c, 0, 0, 0)

__global__ void prep_kernel(const float* __restrict__ wqkv,
                            const float* __restrict__ wproj,
                            const float* __restrict__ btab,
                            bf16* __restrict__ wqkvT,
                            bf16* __restrict__ wprojT,
                            float* __restrict__ relb)
{
    const int idx = blockIdx.x * 256 + threadIdx.x;
    if (idx < 544 * 192) {
        const int n = idx / 192, k = idx - n * 192;
        wqkvT[idx] = (bf16)((n < 540 && k < 180) ? wqkv[k * 540 + n] : 0.f);
    } else if (idx < 544 * 192 + 192 * 192) {
        const int r = idx - 544 * 192;
        const int n = r / 192, k = r - n * 192;
        wprojT[r] = (bf16)((n < 180 && k < 180) ? wproj[k * 180 + n] : 0.f);
    } else if (idx < 544 * 192 + 192 * 192 + 6 * 64 * 64) {
        const int r = idx - (544 * 192 + 192 * 192);
        const int h = r >> 12;                  // /4096
        const int ij = r & 4095;
        const int i = ij >> 6, j = ij & 63;
        const int rel = ((i >> 3) - (j >> 3) + 7) * 15 + ((i & 7) - (j & 7) + 7);
        relb[r] = btab[rel * 6 + h];
    }
}

__global__ __launch_bounds__(384, 1)
void swin_mfma(const float* __restrict__ xg_all,
               const float* __restrict__ mask_all,
               const float* __restrict__ bproj,
               const bf16* __restrict__ wqkvT,
               const bf16* __restrict__ wprojT,
               const float* __restrict__ relb,
               float* __restrict__ outg)
{
    __shared__ __align__(16) short smem[79872];
    short* const xb = smem;              // [64][200], later zb
    short* const qb = smem + 12800;      // [64][200]
    short* const kb = smem + 25600;      // [64][200]
    short* const vT = smem + 38400;      // [192][72]
    short* const pb = smem + 52224;      // 6 x [64][72]

    const int b    = blockIdx.x;
    const int tid  = threadIdx.x;
    const int w    = tid >> 6;           // wave 0..5
    const int lane = tid & 63;
    const int l15  = lane & 15;
    const int g    = lane >> 4;          // 0..3

    const float* xg    = xg_all + (size_t)b * 11520;
    const float* maskw = mask_all + (size_t)(b & 1023) * 4096;

    // ---- phase 1: zero qb/kb/vT + xb pad cols; load x -> bf16 xb[i][c]
    {
        uint4* zz = (uint4*)(smem + 12800);          // qb..vT = 39424 shorts = 4928 uint4
        const uint4 z4 = make_uint4(0, 0, 0, 0);
        for (int e = tid; e < 4928; e += 384) zz[e] = z4;
        for (int e = tid; e < 640; e += 384) {       // xb cols [180..200) as u32 pairs
            const int i = e / 10;
            ((unsigned*)(xb + i * 200 + 180))[e - i * 10] = 0u;
        }
        for (int e = tid; e < 5760; e += 384) {      // 64*180/2 float2 loads
            const int i = e / 90;
            const int c = 2 * e - i * 180;
            const float2 v = *reinterpret_cast<const float2*>(xg + 2 * e);
            const unsigned lo = (unsigned)__builtin_bit_cast(unsigned short, (bf16)v.x);
            const unsigned hi = (unsigned)__builtin_bit_cast(unsigned short, (bf16)v.y);
            *reinterpret_cast<unsigned*>(xb + i * 200 + c) = lo | (hi << 16);
        }
    }
    __syncthreads();

    // ---- phase 2: qkv GEMM  (M=64, N=544 -> 34 ntiles, K=192 -> 6 ksteps)
    // wave w owns ntiles {w + 6c : c=0..5, <34}, processed in chunks of <=3
    {
        const int cnt = (w < 4) ? 6 : 5;
        for (int cb = 0; cb < 2; cb++) {
            const int base = cb * 3;
            f32x4 acc[4][3];
            #pragma unroll
            for (int mt = 0; mt < 4; mt++)
                #pragma unroll
                for (int q = 0; q < 3; q++) acc[mt][q] = (f32x4)0.f;

            for (int ks = 0; ks < 6; ks++) {
                bf16x8 af[4];
                #pragma unroll
                for (int mt = 0; mt < 4; mt++)
                    af[mt] = *reinterpret_cast<const bf16x8*>(
                        xb + (16 * mt + l15) * 200 + 32 * ks + 8 * g);
                #pragma unroll
                for (int q = 0; q < 3; q++) {
                    if (base + q < cnt) {
                        const int nt = w + 6 * (base + q);
                        const bf16x8 bf = *reinterpret_cast<const bf16x8*>(
                            wqkvT + (16 * nt + l15) * 192 + 32 * ks + 8 * g);
                        #pragma unroll
                        for (int mt = 0; mt < 4; mt++)
                            acc[mt][q] = MFMA(af[mt], bf, acc[mt][q]);
                    }
                }
            }
            // epilogue: scatter columns to qb (scaled), kb, vT (transposed)
            #pragma unroll
            for (int q = 0; q < 3; q++) {
                if (base + q >= cnt) continue;
                const int m = 16 * (w + 6 * (base + q)) + l15;
                if (m >= 540) continue;
                const int sec = (m >= 360) ? 2 : (m >= 180 ? 1 : 0);
                const int c = m - sec * 180;
                const int hh = c / 30;
                const int dd = c - hh * 30;
                if (sec == 2) {
                    #pragma unroll
                    for (int mt = 0; mt < 4; mt++) {
                        bf16x4 pk;
                        pk[0] = (bf16)acc[mt][q][0]; pk[1] = (bf16)acc[mt][q][1];
                        pk[2] = (bf16)acc[mt][q][2]; pk[3] = (bf16)acc[mt][q][3];
                        *reinterpret_cast<bf16x4*>(
                            vT + (hh * 32 + dd) * 72 + 16 * mt + 4 * g) = pk;
                    }
                } else {
                    short* const dst = sec ? kb : qb;
                    const float sc = sec ? 1.0f : 0.18257418583505537f;  // fold 1/sqrt(30) into q
                    #pragma unroll
                    for (int mt = 0; mt < 4; mt++)
                        #pragma unroll
                        for (int r = 0; r < 4; r++) {
                            const int i = 16 * mt + 4 * g + r;
                            dst[i * 200 + hh * 32 + dd] =
                                __builtin_bit_cast(short, (bf16)(acc[mt][q][r] * sc));
                        }
                }
            }
        }
    }
    __syncthreads();

    // ---- phase 3: per-head (wave w = head h) swapped QK^T + softmax -> pb
    const int h = w;
    short* const pbh = pb + h * 4608;    // [64][72]
    {
        bf16x8 kf[4], qf[4];
        #pragma unroll
        for (int t = 0; t < 4; t++) {
            kf[t] = *reinterpret_cast<const bf16x8*>(kb + (16 * t + l15) * 200 + h * 32 + 8 * g);
            qf[t] = *reinterpret_cast<const bf16x8*>(qb + (16 * t + l15) * 200 + h * 32 + 8 * g);
        }
        f32x4 st[4][4];                   // [jt][it]: S^T tile; lane: j=16jt+4g+r, i=16it+l15
        #pragma unroll
        for (int jt = 0; jt < 4; jt++)
            #pragma unroll
            for (int it = 0; it < 4; it++)
                st[jt][it] = MFMA(kf[jt], qf[it], (f32x4)0.f);

        #pragma unroll
        for (int it = 0; it < 4; it++) {
            const int i = l15 + 16 * it;
            const float* rbb = relb + (h * 64 + i) * 64;
            const float* mkb = maskw + i * 64;
            float mx = -1e30f;
            #pragma unroll
            for (int jt = 0; jt < 4; jt++) {
                const float4 rb = *reinterpret_cast<const float4*>(rbb + 16 * jt + 4 * g);
                const float4 mk = *reinterpret_cast<const float4*>(mkb + 16 * jt + 4 * g);
                const float rv[4] = {rb.x, rb.y, rb.z, rb.w};
                const float mv[4] = {mk.x, mk.y, mk.z, mk.w};
                #pragma unroll
                for (int r = 0; r < 4; r++) {
                    const float v = st[jt][it][r] + rv[r] + mv[r];
                    st[jt][it][r] = v;
                    mx = fmaxf(mx, v);
                }
            }
            mx = fmaxf(mx, __shfl_xor(mx, 16));
            mx = fmaxf(mx, __shfl_xor(mx, 32));
            float sum = 0.f;
            #pragma unroll
            for (int jt = 0; jt < 4; jt++)
                #pragma unroll
                for (int r = 0; r < 4; r++) {
                    const float e = __expf(st[jt][it][r] - mx);
                    st[jt][it][r] = e;
                    sum += e;
                }
            sum += __shfl_xor(sum, 16);
            sum += __shfl_xor(sum, 32);
            const float inv = 1.0f / sum;
            #pragma unroll
            for (int jt = 0; jt < 4; jt++) {
                bf16x4 pk;
                pk[0] = (bf16)(st[jt][it][0] * inv); pk[1] = (bf16)(st[jt][it][1] * inv);
                pk[2] = (bf16)(st[jt][it][2] * inv); pk[3] = (bf16)(st[jt][it][3] * inv);
                *reinterpret_cast<bf16x4*>(pbh + i * 72 + 16 * jt + 4 * g) = pk;
            }
        }
    }
    __syncthreads();

    // ---- phase 4: PV (A=P from pbh, B=V from vT) -> zb (= xb) bf16; zero zb pad cols
    {
        for (int e = tid; e < 768; e += 384) {       // zb cols [180..192) zero
            const int i = e / 12;
            xb[i * 200 + 180 + (e - i * 12)] = 0;
        }
        f32x4 z[4][2];
        #pragma unroll
        for (int mt = 0; mt < 4; mt++) { z[mt][0] = (f32x4)0.f; z[mt][1] = (f32x4)0.f; }
        #pragma unroll
        for (int ks = 0; ks < 2; ks++) {
            bf16x8 pf[4];
            #pragma unroll
            for (int mt = 0; mt < 4; mt++)
                pf[mt] = *reinterpret_cast<const bf16x8*>(
                    pbh + (l15 + 16 * mt) * 72 + 32 * ks + 8 * g);
            #pragma unroll
            for (int nt = 0; nt < 2; nt++) {
                const bf16x8 vf = *reinterpret_cast<const bf16x8*>(
                    vT + (h * 32 + l15 + 16 * nt) * 72 + 32 * ks + 8 * g);
                #pragma unroll
                for (int mt = 0; mt < 4; mt++)
                    z[mt][nt] = MFMA(pf[mt], vf, z[mt][nt]);
            }
        }
        #pragma unroll
        for (int nt = 0; nt < 2; nt++) {
            const int d = l15 + 16 * nt;
            if (d < 30) {
                #pragma unroll
                for (int mt = 0; mt < 4; mt++)
                    #pragma unroll
                    for (int r = 0; r < 4; r++) {
                        const int i = 16 * mt + 4 * g + r;
                        xb[i * 200 + h * 30 + d] =
                            __builtin_bit_cast(short, (bf16)z[mt][nt][r]);
                    }
            }
        }
    }
    __syncthreads();

    // ---- phase 5: proj GEMM (A=zb, B=wprojT global) + bias -> out
    {
        f32x4 pa[4][2];
        #pragma unroll
        for (int mt = 0; mt < 4; mt++) { pa[mt][0] = (f32x4)0.f; pa[mt][1] = (f32x4)0.f; }
        for (int ks = 0; ks < 6; ks++) {
            bf16x8 zf[4];
            #pragma unroll
            for (int mt = 0; mt < 4; mt++)
                zf[mt] = *reinterpret_cast<const bf16x8*>(
                    xb + (16 * mt + l15) * 200 + 32 * ks + 8 * g);
            #pragma unroll
            for (int q = 0; q < 2; q++) {
                const int nt = 2 * w + q;
                const bf16x8 wf = *reinterpret_cast<const bf16x8*>(
                    wprojT + (16 * nt + l15) * 192 + 32 * ks + 8 * g);
                #pragma unroll
                for (int mt = 0; mt < 4; mt++)
                    pa[mt][q] = MFMA(zf[mt], wf, pa[mt][q]);
            }
        }
        #pragma unroll
        for (int q = 0; q < 2; q++) {
            const int n = 16 * (2 * w + q) + l15;
            if (n >= 180) continue;
            const float bn = bproj[n];
            float* const ob = outg + (size_t)b * 11520 + n;
            #pragma unroll
            for (int mt = 0; mt < 4; mt++)
                #pragma unroll
                for (int r = 0; r < 4; r++) {
                    const int i = 16 * mt + 4 * g + r;
                    ob[i * 180] = pa[mt][q][r] + bn;
                    (void)0;
                }
        }
    }
}

extern "C" void kernel_launch(void* const* d_in, const int* in_sizes, int n_in,
                              void* d_out, int out_size, void* d_ws, size_t ws_size,
                              hipStream_t stream) {
    const float* windows = (const float*)d_in[0];
    const float* mask    = (const float*)d_in[1];
    const float* wqkv    = (const float*)d_in[2];
    const float* btab    = (const float*)d_in[3];
    const float* wproj   = (const float*)d_in[4];
    const float* bproj   = (const float*)d_in[5];

    bf16*  wqkvT  = (bf16*)d_ws;
    bf16*  wprojT = (bf16*)((char*)d_ws + 208896);
    float* relb   = (float*)((char*)d_ws + 282624);

    hipLaunchKernelGGL(prep_kernel, dim3(648), dim3(256), 0, stream,
                       wqkv, wproj, btab, wqkvT, wprojT, relb);
    hipLaunchKernelGGL(swin_mfma, dim3(4096), dim3(384), 0, stream,
                       windows, mask, bproj, wqkvT, wprojT, relb, (float*)d_out);
}